// Round 3
// baseline (1154.167 us; speedup 1.0000x reference)
//
#include <hip/hip_runtime.h>
#include <hip/hip_bf16.h>
#include <math.h>

// GIN + TopK pooling, 4 layers. N=50000, E=600000, B=256, F=H=128, ratio=0.8.
// R3: k_mlp XOR-swizzled sA (kills 4-way A-read conflicts; padding can't fix
// 8-row strides), col remap 4tc/64+4tc (W-reads 2-way = free), 16-row W chunk
// -> LDS 40960 = exactly 4 blocks/CU. score+bnfinal+topk+pool fused into one
// per-graph kernel (BN applied on the fly from raw stats). k_agg unroll x2.

#define HF 128  // feature dim

// ---------------- setup kernels ----------------

__global__ void k_init_mask(int* mask, int n) {
    int i = blockIdx.x * blockDim.x + threadIdx.x;
    if (i < n) mask[i] = 1;
}

__global__ void k_deg(const int* __restrict__ dst, int* __restrict__ deg, int E) {
    int e = blockIdx.x * blockDim.x + threadIdx.x;
    if (e < E) atomicAdd(&deg[dst[e]], 1);
}

__global__ void k_gcnt(const int* __restrict__ batch, int* __restrict__ gcnt, int N) {
    int n = blockIdx.x * blockDim.x + threadIdx.x;
    if (n < N) atomicAdd(&gcnt[batch[n]], 1);
}

// single-block exclusive scan; out[n] = total. launch with T threads (<=1024).
__global__ void k_scan(const int* __restrict__ in, int* __restrict__ out, int n) {
    __shared__ int ss[1024];
    int T = blockDim.x, t = threadIdx.x;
    int C = (n + T - 1) / T;
    int beg = t * C;
    int end = beg + C; if (end > n) end = n;
    int s = 0;
    for (int i = beg; i < end; ++i) s += in[i];
    ss[t] = s;
    __syncthreads();
    for (int off = 1; off < T; off <<= 1) {
        int v = (t >= off) ? ss[t - off] : 0;
        __syncthreads();
        ss[t] += v;
        __syncthreads();
    }
    int run = (t == 0) ? 0 : ss[t - 1];
    for (int i = beg; i < end; ++i) { int d = in[i]; out[i] = run; run += d; }
    if (t == T - 1) out[n] = ss[T - 1];
}

__global__ void k_fill(const int* __restrict__ src, const int* __restrict__ dst,
                       const int* __restrict__ indptr, int* __restrict__ fill,
                       int* __restrict__ csr, int E) {
    int e = blockIdx.x * blockDim.x + threadIdx.x;
    if (e >= E) return;
    int d = dst[e];
    int p = atomicAdd(&fill[d], 1);
    csr[indptr[d] + p] = src[e];
}

// ---------------- per-layer kernels ----------------

// one wave per node, 32 lanes x float4, 2 edge streams, inner unroll 2
// (4 loads in flight per wave).
__global__ __launch_bounds__(256)
void k_agg(const float* __restrict__ x, const int* __restrict__ indptr,
           const int* __restrict__ csr, float* __restrict__ agg, int N) {
    int wid = (blockIdx.x * 256 + threadIdx.x) >> 6;
    int lane = threadIdx.x & 63;
    if (wid >= N) return;
    int half = lane >> 5;          // which edge stream
    int c = (lane & 31) * 4;       // col chunk
    int beg = indptr[wid], end = indptr[wid + 1];
    float4 acc = make_float4(0.f, 0.f, 0.f, 0.f);
    float4 acc2 = make_float4(0.f, 0.f, 0.f, 0.f);
    int e = beg + half;
    for (; e + 2 < end; e += 4) {
        int s0 = csr[e], s1 = csr[e + 2];
        float4 v0 = *(const float4*)&x[(size_t)s0 * HF + c];
        float4 v1 = *(const float4*)&x[(size_t)s1 * HF + c];
        acc.x += v0.x; acc.y += v0.y; acc.z += v0.z; acc.w += v0.w;
        acc2.x += v1.x; acc2.y += v1.y; acc2.z += v1.z; acc2.w += v1.w;
    }
    if (e < end) {
        int s0 = csr[e];
        float4 v0 = *(const float4*)&x[(size_t)s0 * HF + c];
        acc.x += v0.x; acc.y += v0.y; acc.z += v0.z; acc.w += v0.w;
    }
    acc.x += acc2.x; acc.y += acc2.y; acc.z += acc2.z; acc.w += acc2.w;
    acc.x += __shfl_down(acc.x, 32);
    acc.y += __shfl_down(acc.y, 32);
    acc.z += __shfl_down(acc.z, 32);
    acc.w += __shfl_down(acc.w, 32);
    if (half == 0) *(float4*)&agg[(size_t)wid * HF + c] = acc;
}

// Fused MLP + BN-stats. 64 rows/block, 128 threads (8 row-grp x 16 col-grp),
// 8x8 register tile. sA[64][128] XOR-swizzled on float4 slot (kq ^ (r>>3)&3):
// A-reads conflict-free. Cols per thread: {4tc..4tc+3} u {64+4tc..}: W-reads
// 2-way (free). sW 16-row chunks. LDS = 40960 B -> 4 blocks/CU, 8 waves/CU.
__global__ __launch_bounds__(128)
void k_mlp(const float* __restrict__ x, const float* __restrict__ agg,
           const float* __restrict__ W1, const float* __restrict__ b1,
           const float* __restrict__ W2, const float* __restrict__ b2,
           const int* __restrict__ mask, float* __restrict__ h,
           float* __restrict__ stats, int N) {
    __shared__ float sA[64 * 128];   // 32 KB: input tile, then h1, then scratch
    __shared__ float sW[16 * 128];   // 8 KB: W k-chunk
    int tid = threadIdx.x;
    int row0 = blockIdx.x * 64;
    int tr = tid >> 4, tc = tid & 15;   // tr 0..7, tc 0..15
    int r0 = tr * 8;
    int swz = tr & 3;                   // float4-slot xor for this thread's rows

    // stage sA = x + agg (swizzled)
#pragma unroll
    for (int it = 0; it < 16; ++it) {
        int flat4 = it * 128 + tid;          // 0..2047 float4 slots
        int r = flat4 >> 5, kq = flat4 & 31;
        int row = row0 + r;
        float4 v = make_float4(0.f, 0.f, 0.f, 0.f);
        if (row < N) {
            float4 a = *(const float4*)&x[(size_t)row * HF + kq * 4];
            float4 g = *(const float4*)&agg[(size_t)row * HF + kq * 4];
            v = make_float4(a.x + g.x, a.y + g.y, a.z + g.z, a.w + g.w);
        }
        *(float4*)&sA[r * 128 + (kq ^ ((r >> 3) & 3)) * 4] = v;
    }

    float acc[8][8];
#pragma unroll
    for (int i = 0; i < 8; ++i)
#pragma unroll
        for (int j = 0; j < 8; ++j) acc[i][j] = 0.f;

    // ---- GEMM1: 8 chunks of k=16 ----
    for (int kb = 0; kb < 8; ++kb) {
        __syncthreads();   // prev chunk consumed (covers sA staging on kb=0)
#pragma unroll
        for (int it = 0; it < 4; ++it) {
            int flat4 = it * 128 + tid;      // 0..511
            int kr = flat4 >> 5, kq = flat4 & 31;
            *(float4*)&sW[kr * 128 + kq * 4] =
                *(const float4*)&W1[(size_t)(kb * 16 + kr) * HF + kq * 4];
        }
        __syncthreads();
#pragma unroll
        for (int k4 = 0; k4 < 4; ++k4) {
            int kq = kb * 4 + k4;            // global float4 slot
            int kk = k4 * 4;                 // local k in chunk
            float4 a[8];
#pragma unroll
            for (int i = 0; i < 8; ++i)
                a[i] = *(const float4*)&sA[(r0 + i) * 128 + (kq ^ swz) * 4];
#pragma unroll
            for (int t = 0; t < 4; ++t) {
                float4 w0 = *(const float4*)&sW[(kk + t) * 128 + tc * 4];
                float4 w1 = *(const float4*)&sW[(kk + t) * 128 + 64 + tc * 4];
                float wv[8] = {w0.x, w0.y, w0.z, w0.w, w1.x, w1.y, w1.z, w1.w};
#pragma unroll
                for (int i = 0; i < 8; ++i) {
                    float av = ((const float*)&a[i])[t];
#pragma unroll
                    for (int j = 0; j < 8; ++j)
                        acc[i][j] = fmaf(av, wv[j], acc[i][j]);
                }
            }
        }
    }

    // h1 = relu(acc + b1) -> back into sA (swizzled)
    float4 b1lo = *(const float4*)&b1[tc * 4];
    float4 b1hi = *(const float4*)&b1[64 + tc * 4];
    __syncthreads();   // all GEMM1 reads of sA done
    int slo = (tc ^ swz) * 4;
    int shi = ((16 + tc) ^ swz) * 4;
#pragma unroll
    for (int i = 0; i < 8; ++i) {
        float4 lo = make_float4(fmaxf(acc[i][0] + b1lo.x, 0.f), fmaxf(acc[i][1] + b1lo.y, 0.f),
                                fmaxf(acc[i][2] + b1lo.z, 0.f), fmaxf(acc[i][3] + b1lo.w, 0.f));
        float4 hi = make_float4(fmaxf(acc[i][4] + b1hi.x, 0.f), fmaxf(acc[i][5] + b1hi.y, 0.f),
                                fmaxf(acc[i][6] + b1hi.z, 0.f), fmaxf(acc[i][7] + b1hi.w, 0.f));
        *(float4*)&sA[(r0 + i) * 128 + slo] = lo;
        *(float4*)&sA[(r0 + i) * 128 + shi] = hi;
#pragma unroll
        for (int j = 0; j < 8; ++j) acc[i][j] = 0.f;
    }

    // ---- GEMM2 ----
    for (int kb = 0; kb < 8; ++kb) {
        __syncthreads();
#pragma unroll
        for (int it = 0; it < 4; ++it) {
            int flat4 = it * 128 + tid;
            int kr = flat4 >> 5, kq = flat4 & 31;
            *(float4*)&sW[kr * 128 + kq * 4] =
                *(const float4*)&W2[(size_t)(kb * 16 + kr) * HF + kq * 4];
        }
        __syncthreads();
#pragma unroll
        for (int k4 = 0; k4 < 4; ++k4) {
            int kq = kb * 4 + k4;
            int kk = k4 * 4;
            float4 a[8];
#pragma unroll
            for (int i = 0; i < 8; ++i)
                a[i] = *(const float4*)&sA[(r0 + i) * 128 + (kq ^ swz) * 4];
#pragma unroll
            for (int t = 0; t < 4; ++t) {
                float4 w0 = *(const float4*)&sW[(kk + t) * 128 + tc * 4];
                float4 w1 = *(const float4*)&sW[(kk + t) * 128 + 64 + tc * 4];
                float wv[8] = {w0.x, w0.y, w0.z, w0.w, w1.x, w1.y, w1.z, w1.w};
#pragma unroll
                for (int i = 0; i < 8; ++i) {
                    float av = ((const float*)&a[i])[t];
#pragma unroll
                    for (int j = 0; j < 8; ++j)
                        acc[i][j] = fmaf(av, wv[j], acc[i][j]);
                }
            }
        }
    }

    // epilogue: bias2, store raw h, masked BN stats
    float4 b2lo = *(const float4*)&b2[tc * 4];
    float4 b2hi = *(const float4*)&b2[64 + tc * 4];
    float bset[8] = {b2lo.x, b2lo.y, b2lo.z, b2lo.w, b2hi.x, b2hi.y, b2hi.z, b2hi.w};
    float s_loc[8], q_loc[8];
#pragma unroll
    for (int j = 0; j < 8; ++j) { s_loc[j] = 0.f; q_loc[j] = 0.f; }
#pragma unroll
    for (int i = 0; i < 8; ++i) {
        int row = row0 + r0 + i;
        if (row >= N) continue;
        float v[8];
#pragma unroll
        for (int j = 0; j < 8; ++j) v[j] = acc[i][j] + bset[j];
        *(float4*)&h[(size_t)row * HF + tc * 4]      = make_float4(v[0], v[1], v[2], v[3]);
        *(float4*)&h[(size_t)row * HF + 64 + tc * 4] = make_float4(v[4], v[5], v[6], v[7]);
        if (mask[row]) {
#pragma unroll
            for (int j = 0; j < 8; ++j) { s_loc[j] += v[j]; q_loc[j] += v[j] * v[j]; }
        }
    }
    __syncthreads();   // all GEMM2 LDS reads done; reuse sA as scratch
    *(float4*)&sA[tr * 128 + tc * 4]             = make_float4(s_loc[0], s_loc[1], s_loc[2], s_loc[3]);
    *(float4*)&sA[tr * 128 + 64 + tc * 4]        = make_float4(s_loc[4], s_loc[5], s_loc[6], s_loc[7]);
    *(float4*)&sA[1024 + tr * 128 + tc * 4]      = make_float4(q_loc[0], q_loc[1], q_loc[2], q_loc[3]);
    *(float4*)&sA[1024 + tr * 128 + 64 + tc * 4] = make_float4(q_loc[4], q_loc[5], q_loc[6], q_loc[7]);
    __syncthreads();
    if (tid < 128) {
        float s = 0.f, q = 0.f;
#pragma unroll
        for (int r = 0; r < 8; ++r) { s += sA[r * 128 + tid]; q += sA[1024 + r * 128 + tid]; }
        atomicAdd(&stats[tid], s);
        atomicAdd(&stats[128 + tid], q);
    }
    if (tid < 64) {
        int row = row0 + tid;
        bool live = (row < N) && mask[row];
        unsigned long long bal = __ballot(live);
        if (tid == 0) atomicAdd(&stats[256], (float)__popcll(bal));
    }
}

// One block per graph: inline BN-finalize from raw stats, per-node score
// (BN+relu+dot on the fly), bitonic top-k, then x-update + max/mean pool.
__global__ __launch_bounds__(256)
void k_topkpool(const float* __restrict__ h, const float* __restrict__ stats,
                const float* __restrict__ gamma, const float* __restrict__ beta,
                const float* __restrict__ w, int* __restrict__ mask,
                const int* __restrict__ gstart, float* __restrict__ x,
                float* __restrict__ out, int N) {
    __shared__ unsigned long long skey[512];
    __shared__ float sscore[512];
    __shared__ float sscale[128], sshift[128], swv[128], sred[128];
    __shared__ float smx[128], ssum[128];
    __shared__ int s_live;
    int b = blockIdx.x, tid = threadIdx.x;
    int gs = gstart[b], ge = gstart[b + 1];
    int size = ge - gs;
    if (size > 512) size = 512;  // statistically impossible
    int M = (size <= 256) ? 256 : 512;
    if (tid == 0) s_live = 0;
    if (tid < 128) { float wc = w[tid]; swv[tid] = wc; sred[tid] = wc * wc; }
    __syncthreads();
    for (int off = 64; off; off >>= 1) {
        if (tid < off) sred[tid] += sred[tid + off];
        __syncthreads();
    }
    float normv = sqrtf(sred[0]);
    if (tid < 128) {
        float n = fmaxf(stats[256], 1.0f);
        float mean = stats[tid] / n;
        float var = fmaxf(stats[128 + tid] / n - mean * mean, 0.f);
        float sc = gamma[tid] * rsqrtf(var + 1e-5f);
        sscale[tid] = sc;
        sshift[tid] = beta[tid] - mean * sc;
    }
    __syncthreads();

    // phase 1: per-node scores + sort keys (wave per node)
    int wv = tid >> 6, lane = tid & 63;
    int lc = 0;
    for (int j = wv; j < M; j += 4) {
        unsigned long long key = (0xFFFFFFFFull << 32) | (unsigned)j;
        bool live = (j < size) && (mask[gs + j] != 0);
        if (live) {
            int c = lane * 2;
            float2 v = *(const float2*)&h[(size_t)(gs + j) * HF + c];
            float a0 = fmaxf(fmaf(v.x, sscale[c], sshift[c]), 0.f);
            float a1 = fmaxf(fmaf(v.y, sscale[c + 1], sshift[c + 1]), 0.f);
            float s = a0 * swv[c] + a1 * swv[c + 1];
#pragma unroll
            for (int off = 32; off; off >>= 1) s += __shfl_down(s, off, 64);
            if (lane == 0) {
                float scv = s / normv;
                sscore[j] = scv;
                unsigned u = __float_as_uint(scv);
                u = (u & 0x80000000u) ? ~u : (u | 0x80000000u);
                key = (((unsigned long long)(~u)) << 32) | (unsigned)j;
            }
        }
        if (lane == 0) { skey[j] = key; if (live) lc++; }
    }
    if (lane == 0 && lc) atomicAdd(&s_live, lc);
    __syncthreads();

    // bitonic sort (score desc, idx asc)
    for (int k = 2; k <= M; k <<= 1) {
        for (int jj = k >> 1; jj > 0; jj >>= 1) {
            for (int t = tid; t < M; t += 256) {
                int ixj = t ^ jj;
                if (ixj > t) {
                    bool up = ((t & k) == 0);
                    unsigned long long A = skey[t], Bv = skey[ixj];
                    if ((A > Bv) == up) { skey[t] = Bv; skey[ixj] = A; }
                }
            }
            __syncthreads();
        }
    }
    int live = s_live;
    int kk = (live > 0) ? (int)ceilf(0.8f * (float)live) : 0;  // jnp f32 ceil

    // tanh once per node
    for (int j = tid; j < size; j += 256) sscore[j] = tanhf(sscore[j]);
    __syncthreads();

    // phase 2: x-update + mask + max/mean pool (2 nodes per iteration)
    int f = tid & 127, hf = tid >> 7;
    float mx = -INFINITY, sum = 0.f;
    for (int p = hf; p < M; p += 2) {
        int local = (int)(skey[p] & 0xFFFFFFFFu);
        if (local >= size) continue;
        int node = gs + local;
        float v = 0.f;
        bool keep = (p < kk);
        if (keep) {
            float hv = h[(size_t)node * HF + f];
            hv = fmaxf(fmaf(hv, sscale[f], sshift[f]), 0.f);
            v = hv * sscore[local];
            mx = fmaxf(mx, v);
            sum += v;
        }
        x[(size_t)node * HF + f] = v;
        if (f == 0) mask[node] = keep ? 1 : 0;
    }
    if (hf) { smx[f] = mx; ssum[f] = sum; }
    __syncthreads();
    if (!hf) {
        mx = fmaxf(mx, smx[f]);
        sum += ssum[f];
        float mxo = (kk > 0) ? mx : 0.f;
        float mn = sum / (float)(kk > 0 ? kk : 1);
        out[b * 256 + f] += mxo;
        out[b * 256 + 128 + f] += mn;
    }
}

// ---------------- launcher ----------------

extern "C" void kernel_launch(void* const* d_in, const int* in_sizes, int n_in,
                              void* d_out, int out_size, void* d_ws, size_t ws_size,
                              hipStream_t stream) {
    const float* x_in    = (const float*)d_in[0];
    const int*   ei      = (const int*)d_in[1];
    const int*   batch   = (const int*)d_in[2];
    const float* W1s     = (const float*)d_in[3];
    const float* b1s     = (const float*)d_in[4];
    const float* W2s     = (const float*)d_in[5];
    const float* b2s     = (const float*)d_in[6];
    const float* gammas  = (const float*)d_in[7];
    const float* betas   = (const float*)d_in[8];
    const float* pool_ws = (const float*)d_in[9];

    int N = in_sizes[0] / HF;
    int E = in_sizes[1] / 2;
    int B = out_size / (2 * HF);
    const int* src = ei;
    const int* dst = ei + E;

    char* ws = (char*)d_ws;
    size_t off = 0;
    auto alloc = [&](size_t bytes) -> void* {
        void* p = ws + off;
        off = (off + bytes + 255) & ~(size_t)255;
        return p;
    };
    float* agg    = (float*)alloc((size_t)N * HF * 4);
    float* h      = (float*)alloc((size_t)N * HF * 4);
    float* xbuf   = (float*)alloc((size_t)N * HF * 4);
    int*   mask   = (int*)alloc((size_t)N * 4);
    int*   deg    = (int*)alloc((size_t)(N + 1) * 4);
    int*   indptr = (int*)alloc((size_t)(N + 1) * 4);
    int*   fill   = (int*)alloc((size_t)N * 4);
    int*   csr    = (int*)alloc((size_t)E * 4);
    int*   gcnt   = (int*)alloc((size_t)B * 4);
    int*   gstart = (int*)alloc((size_t)(B + 1) * 4);
    float* stats  = (float*)alloc(257 * 4);
    float* out    = (float*)d_out;

    hipMemsetAsync(d_out, 0, (size_t)out_size * 4, stream);
    hipMemsetAsync(deg, 0, (size_t)(N + 1) * 4, stream);
    hipMemsetAsync(fill, 0, (size_t)N * 4, stream);
    hipMemsetAsync(gcnt, 0, (size_t)B * 4, stream);

    int tb = 256;
    k_init_mask<<<(N + tb - 1) / tb, tb, 0, stream>>>(mask, N);
    k_deg<<<(E + tb - 1) / tb, tb, 0, stream>>>(dst, deg, E);
    k_gcnt<<<(N + tb - 1) / tb, tb, 0, stream>>>(batch, gcnt, N);
    k_scan<<<1, 1024, 0, stream>>>(deg, indptr, N);
    k_scan<<<1, 256, 0, stream>>>(gcnt, gstart, B);
    k_fill<<<(E + tb - 1) / tb, tb, 0, stream>>>(src, dst, indptr, fill, csr, E);

    for (int i = 0; i < 4; ++i) {
        const float* xc = (i == 0) ? x_in : xbuf;
        hipMemsetAsync(stats, 0, 257 * 4, stream);
        k_agg<<<(N + 3) / 4, 256, 0, stream>>>(xc, indptr, csr, agg, N);
        k_mlp<<<(N + 63) / 64, 128, 0, stream>>>(xc, agg, W1s + i * 16384, b1s + i * 128,
                                                 W2s + i * 16384, b2s + i * 128,
                                                 mask, h, stats, N);
        k_topkpool<<<B, 256, 0, stream>>>(h, stats, gammas + i * 128, betas + i * 128,
                                          pool_ws + i * 128, mask, gstart, xbuf, out, N);
    }
}